// Round 20
// baseline (188.141 us; speedup 1.0000x reference)
//
#include <hip/hip_runtime.h>
#include <math.h>

#define B_DIM 8
#define S_DIM 4096
#define D_DIM 1024
#define N_DIM 16
#define ROWS (B_DIM * S_DIM)          // 32768

#define CHUNK_L 32
#define WARM 64
#define STEPS (CHUNK_L + WARM)        // 96
#define NCHAIN (B_DIM * (S_DIM / CHUNK_L))   // 1024 chains

#define XB_BLOCKS (ROWS / 16)         // 2048 blocks: 4 waves x 4 rows each
#define CW_BLOCKS ((N_DIM * D_DIM) / 256)   // 64

typedef float f32x4 __attribute__((ext_vector_type(4)));

// ---------------------------------------------------------------------------
// k_prep: Bt[n][k] = B[k][n]  (transpose, 64 KB; R19-proven correct)
// ---------------------------------------------------------------------------
__global__ __launch_bounds__(256) void k_prep(const float* __restrict__ Bm,
                                              float* __restrict__ Bt) {
    int t = threadIdx.x;
    int n = t >> 4;
    int kb = (t & 15) * 64;
#pragma unroll 8
    for (int j = 0; j < 64; ++j)
        Bt[n * D_DIM + kb + j] = Bm[(size_t)(kb + j) * N_DIM + n];
}

// fold 16 per-lane partials (a[n] = lane's k-slice sum for output n) into
// full 64-lane sums. Returns lane l's value for n = nmap(l&15) where
// nmap = bit-reverse-4(l). 17 shuffles total (8+4+2+1+1+1).
__device__ __forceinline__ float fold16(const float* a, int l) {
    float h0, h1, h2, h3, h4, h5, h6, h7;
#define ST1(J, H)                                                          \
    {                                                                      \
        float ex = (l & 1) ? a[J] : a[J + 8];                              \
        float kp = (l & 1) ? a[J + 8] : a[J];                              \
        H = kp + __shfl_xor(ex, 1, 64);                                    \
    }
    ST1(0, h0) ST1(1, h1) ST1(2, h2) ST1(3, h3)
    ST1(4, h4) ST1(5, h5) ST1(6, h6) ST1(7, h7)
#undef ST1
    float g0, g1, g2, g3;
#define ST2(A, B, G)                                                       \
    {                                                                      \
        float ex = (l & 2) ? (A) : (B);                                    \
        float kp = (l & 2) ? (B) : (A);                                    \
        G = kp + __shfl_xor(ex, 2, 64);                                    \
    }
    ST2(h0, h4, g0) ST2(h1, h5, g1) ST2(h2, h6, g2) ST2(h3, h7, g3)
#undef ST2
    float f0, f1;
    {
        float ex = (l & 4) ? g0 : g2;
        float kp = (l & 4) ? g2 : g0;
        f0 = kp + __shfl_xor(ex, 4, 64);
        ex = (l & 4) ? g1 : g3;
        kp = (l & 4) ? g3 : g1;
        f1 = kp + __shfl_xor(ex, 4, 64);
    }
    float e;
    {
        float ex = (l & 8) ? f0 : f1;
        float kp = (l & 8) ? f1 : f0;
        e = kp + __shfl_xor(ex, 8, 64);
    }
    e += __shfl_xor(e, 16, 64);
    e += __shfl_xor(e, 32, 64);
    return e;
}

// ---------------------------------------------------------------------------
// Kernel 1 (fused): blocks [0,2048): xb = x@B, wave-per-4-rows.
//  The 14-variant post-mortem model: B-operand bytes are the universal wall
//  (DS-broadcast / TA-per-lane / SMEM all lose at N=16). This structure
//  amortizes B over 4 rows and keeps EVERY load k_diag-shaped (1KB
//  contiguous per instr, the proven-5.4TB/s pattern):
//   - x: lane l reads x[row][kb*256+4l..+3], 4 rows x 4 kb = 16 instrs/wave.
//   - B^T: lane l reads Bt[n][kb*256+4l..+3], kb-OUTER so the 16KB B-window
//     is L1-resident across waves; 64 instrs/wave, amortized 4 rows.
//   - reduction: in-register over kb, then 17-shuffle butterfly fold per
//     row (DS ~5.4us/CU). No LDS storage, no barriers, no k_red pass.
//  Budget/CU: HBM 21us | L2-B 15 | VALU 6.8 | DS 5.4 | TA 4 -> ~25-35us.
// blocks [2048,2112): CW[n][d] = sum_k C[n][k]*W[d][k]  (round-1 proven).
// ---------------------------------------------------------------------------
__global__ __launch_bounds__(256) void k_xbcw(const float* __restrict__ x,
                                              const float* __restrict__ Bt,
                                              float* __restrict__ xb,
                                              const float* __restrict__ C,
                                              const float* __restrict__ W,
                                              float* __restrict__ CW) {
    const int t = threadIdx.x;
    if (blockIdx.x >= XB_BLOCKS) {
        int u = (blockIdx.x - XB_BLOCKS) * 256 + t;
        int d = u >> 4;
        int n = u & 15;
        const float* crow = C + n * D_DIM;
        const float* wrow = W + (size_t)d * D_DIM;
        float acc = 0.f;
#pragma unroll 4
        for (int k = 0; k < D_DIM; k += 4) {
            float4 c4 = *(const float4*)(crow + k);
            float4 w4 = *(const float4*)(wrow + k);
            acc = fmaf(c4.x, w4.x, acc);
            acc = fmaf(c4.y, w4.y, acc);
            acc = fmaf(c4.z, w4.z, acc);
            acc = fmaf(c4.w, w4.w, acc);
        }
        CW[n * D_DIM + d] = acc;
        return;
    }
    const int l = t & 63;
    const int w = t >> 6;
    const int row0 = blockIdx.x * 16 + w * 4;
    const float* xr = x + (size_t)row0 * D_DIM + 4 * l;
    const float* btl = Bt + 4 * l;

    float acc[4][16];
#pragma unroll
    for (int r = 0; r < 4; ++r)
#pragma unroll
        for (int n = 0; n < 16; ++n) acc[r][n] = 0.f;

#pragma unroll
    for (int kb = 0; kb < 4; ++kb) {
        f32x4 x0 = *(const f32x4*)(xr + 0 * D_DIM + kb * 256);
        f32x4 x1 = *(const f32x4*)(xr + 1 * D_DIM + kb * 256);
        f32x4 x2 = *(const f32x4*)(xr + 2 * D_DIM + kb * 256);
        f32x4 x3 = *(const f32x4*)(xr + 3 * D_DIM + kb * 256);
        const float* bt = btl + kb * 256;
#pragma unroll
        for (int n = 0; n < 16; ++n) {
            f32x4 b = *(const f32x4*)(bt + (size_t)n * D_DIM);
            acc[0][n] = fmaf(x0[3], b[3], fmaf(x0[2], b[2],
                        fmaf(x0[1], b[1], fmaf(x0[0], b[0], acc[0][n]))));
            acc[1][n] = fmaf(x1[3], b[3], fmaf(x1[2], b[2],
                        fmaf(x1[1], b[1], fmaf(x1[0], b[0], acc[1][n]))));
            acc[2][n] = fmaf(x2[3], b[3], fmaf(x2[2], b[2],
                        fmaf(x2[1], b[1], fmaf(x2[0], b[0], acc[2][n]))));
            acc[3][n] = fmaf(x3[3], b[3], fmaf(x3[2], b[2],
                        fmaf(x3[1], b[1], fmaf(x3[0], b[0], acc[3][n]))));
        }
    }

    // butterfly fold + write; lane l<16 writes n = bit-reverse-4(l)
    const int nmap = ((l & 1) << 3) | ((l & 2) << 1) | ((l & 4) >> 1) |
                     ((l & 8) >> 3);
#pragma unroll
    for (int r = 0; r < 4; ++r) {
        float v = fold16(acc[r], l);
        if (l < 16)
            xb[(size_t)(row0 + r) * N_DIM + nmap] = v;
    }
}

// ---------------------------------------------------------------------------
// Kernel 2: chunked scan (round-6 proven, UNCHANGED)
// ---------------------------------------------------------------------------
__global__ __launch_bounds__(64) void k_scan(const float* __restrict__ xb,
                                             const float* __restrict__ A,
                                             float* __restrict__ hs) {
    const int tid = threadIdx.x;
    const int n = tid & 15;
    const int base4 = (tid & 48) * 4;

    const int chain = blockIdx.x * 4 + (tid >> 4);
    const int b = chain >> 7;
    const int chunk = chain & 127;
    const int t0 = chunk * CHUNK_L - WARM;

    float Ar[16];
#pragma unroll
    for (int m4 = 0; m4 < 16; m4 += 4) {
        float4 v = *(const float4*)(A + n * 16 + m4);
        Ar[m4 + 0] = v.x; Ar[m4 + 1] = v.y; Ar[m4 + 2] = v.z; Ar[m4 + 3] = v.w;
    }

    const float* xp = xb + (size_t)b * S_DIM * N_DIM + n;
    float* hp = hs + (size_t)b * S_DIM * N_DIM + n;

    float ring[8];
#pragma unroll
    for (int i = 0; i < 8; ++i) {
        int tt = t0 + i;
        ring[i] = (tt >= 0) ? xp[(size_t)tt * N_DIM] : 0.f;
    }

    float h = 0.f;
    for (int tr0 = 0; tr0 < STEPS; tr0 += 8) {
#pragma unroll
        for (int j = 0; j < 8; ++j) {
            const int tr = tr0 + j;
            const float xv = ring[j];
            const int hbits = __float_as_int(h);
            int hm[16];
#pragma unroll
            for (int m = 0; m < 16; ++m)
                hm[m] = __builtin_amdgcn_ds_bpermute(base4 + m * 4, hbits);
            float acc0 = xv, acc1 = 0.f;
#pragma unroll
            for (int m = 0; m < 8; ++m) {
                acc0 = fmaf(Ar[m], __int_as_float(hm[m]), acc0);
                acc1 = fmaf(Ar[m + 8], __int_as_float(hm[m + 8]), acc1);
            }
            float g = acc0 + acc1;
            float ax = fabsf(g);
            float e = __expf(2.f * ax);
            float tv = 1.f - 2.f / (e + 1.f);
            h = (g < 0.f) ? -tv : tv;
            if (tr >= WARM)
                hp[(size_t)(t0 + tr) * N_DIM] = h;
            int tt = t0 + tr + 8;
            if (tr + 8 < STEPS)
                ring[j] = (tt >= 0) ? xp[(size_t)tt * N_DIM] : 0.f;
        }
    }
}

// ---------------------------------------------------------------------------
// Kernel 3: out[r][d] = sum_n hs[r][n] * CW[n][d] + bias[d]  (round-1 proven)
// ---------------------------------------------------------------------------
__global__ __launch_bounds__(256) void k_out(const float* __restrict__ hs,
                                             const float* __restrict__ CW,
                                             const float* __restrict__ bias,
                                             float* __restrict__ out) {
    const int t = threadIdx.x;
    const int d0 = t * 4;
    const int row0 = blockIdx.x * 32;
    float4 cw[16];
#pragma unroll
    for (int nn = 0; nn < 16; ++nn)
        cw[nn] = *(const float4*)(CW + nn * D_DIM + d0);
    float4 b4 = *(const float4*)(bias + d0);

    for (int r = row0; r < row0 + 32; ++r) {
        const float4* hp = (const float4*)(hs + (size_t)r * N_DIM);
        float4 h0 = hp[0], h1 = hp[1], h2 = hp[2], h3 = hp[3];
        float hv[16] = {h0.x, h0.y, h0.z, h0.w, h1.x, h1.y, h1.z, h1.w,
                        h2.x, h2.y, h2.z, h2.w, h3.x, h3.y, h3.z, h3.w};
        float4 acc = b4;
#pragma unroll
        for (int nn = 0; nn < 16; ++nn) {
            acc.x = fmaf(hv[nn], cw[nn].x, acc.x);
            acc.y = fmaf(hv[nn], cw[nn].y, acc.y);
            acc.z = fmaf(hv[nn], cw[nn].z, acc.z);
            acc.w = fmaf(hv[nn], cw[nn].w, acc.w);
        }
        *(float4*)(out + (size_t)r * D_DIM + d0) = acc;
    }
}

// ---------------------------------------------------------------------------
extern "C" void kernel_launch(void* const* d_in, const int* in_sizes, int n_in,
                              void* d_out, int out_size, void* d_ws,
                              size_t ws_size, hipStream_t stream) {
    const float* x    = (const float*)d_in[0];   // [8,4096,1024]
    const float* A    = (const float*)d_in[1];   // [16,16]
    const float* Bm   = (const float*)d_in[2];   // [1024,16]
    const float* C    = (const float*)d_in[3];   // [16,1024]
    const float* W    = (const float*)d_in[4];   // [1024,1024]
    const float* bias = (const float*)d_in[5];   // [1024]
    float* out = (float*)d_out;

    float* ws = (float*)d_ws;
    float* xb = ws;                            // 524288 floats
    float* hs = ws + 524288;                   // 524288
    float* CW = ws + 1048576;                  // 16384
    float* Bt = ws + 1064960;                  // 16384

    k_prep<<<dim3(1), dim3(256), 0, stream>>>(Bm, Bt);
    k_xbcw<<<dim3(XB_BLOCKS + CW_BLOCKS), dim3(256), 0, stream>>>(
        x, Bt, xb, C, W, CW);
    k_scan<<<dim3(NCHAIN / 4), dim3(64), 0, stream>>>(xb, A, hs);
    k_out<<<dim3(ROWS / 32), dim3(256), 0, stream>>>(hs, CW, bias, out);
}